// Round 6
// baseline (3510.912 us; speedup 1.0000x reference)
//
#include <hip/hip_runtime.h>
#include <hip/hip_bf16.h>
#include <string.h>

typedef __attribute__((ext_vector_type(8))) short short8;
typedef __attribute__((ext_vector_type(4))) float f32x4;
typedef unsigned long long ull;

#define NN 50000
#define NE 600000
#define GXc 782    // ceil(50000/64)
#define ABc 12500  // ceil(50000/4)
#define RNG 2048   // nodes per LDS-histogram range
#define NR 25      // ceil(50000/2048)

__device__ __forceinline__ unsigned short f32_bf16(float f) {
  unsigned u = __float_as_uint(f);
  unsigned r = u + 0x7FFFu + ((u >> 16) & 1u);
  return (unsigned short)(r >> 16);
}
__device__ __forceinline__ float bf_lo(unsigned v) { return __uint_as_float(v << 16); }
__device__ __forceinline__ float bf_hi(unsigned v) { return __uint_as_float(v & 0xFFFF0000u); }

// ---------------- fused transpose of all 7 weights ----------------
struct TransDesc { const float* src; unsigned short* dst; int K, Nn, Kpad, base; };
struct TransArgs { TransDesc d[7]; int total; };

__global__ void transpose_all_kernel(TransArgs a) {
  int idx = blockIdx.x * 256 + threadIdx.x;
  if (idx >= a.total) return;
  int s = 0;
#pragma unroll
  for (int q = 1; q < 7; ++q)
    if (idx >= a.d[q].base) s = q;
  TransDesc t = a.d[s];
  int off = idx - t.base;
  int n = off / t.Kpad, k = off % t.Kpad;
  float v = (k < t.K) ? t.src[(size_t)k * t.Nn + n] : 0.f;
  t.dst[off] = f32_bf16(v);
}

// ---------------- GEMM body (bf16 MFMA, BM=64, register prefetch, dynamic LDS) ----
template <int BN, bool ABF16, bool PRED>
__device__ __forceinline__ void gemm_body(char* ldsraw, const void* __restrict__ Av,
                                          const unsigned short* __restrict__ BT,
                                          unsigned short* __restrict__ C, int M, int K, int Kpad,
                                          int ldc, const float* fbias, const float* Wp,
                                          const float* bp, float* pout, int bx) {
  constexpr int BM = 64, BK = 32, LW = BK + 8;
  unsigned short* As = (unsigned short*)ldsraw;
  unsigned short* Bs = As + BM * LW;
  const int tid = threadIdx.x;
  const int m0 = bx * BM;
  const int wid = tid >> 6, lane = tid & 63;
  constexpr int WC = (BN == 128) ? 2 : 1;
  constexpr int WTM = (BN == 128) ? 32 : 16;
  constexpr int FM = WTM / 16;
  constexpr int FN = 4;
  const int wr = wid / WC, wc = wid % WC;
  const int rowbase = wr * WTM, colbase = wc * 64;
  const int lrow = lane & 15, lk = lane >> 4;

  const float* Af = (const float*)Av;
  const unsigned short* Ah = (const unsigned short*)Av;

  f32x4 acc[FM][FN] = {};
  float4 arf[2];
  short8 arh;
  short8 brr[BN / 64];

  const int nt = Kpad / BK;

  auto loadA = [&](int k0) {
    if (ABF16) {
      int row = tid >> 2, c8 = tid & 3;
      int gr = m0 + row;
      if (gr >= M) gr = M - 1;
      arh = *(const short8*)(Ah + (size_t)gr * K + k0 + c8 * 8);
    } else {
#pragma unroll
      for (int p = 0; p < 2; ++p) {
        int f = tid + p * 256;
        int row = f >> 3, c4 = f & 7;
        int gr = m0 + row;
        if (gr >= M) gr = M - 1;
        int gk = k0 + c4 * 4;
        float4 v = make_float4(0.f, 0.f, 0.f, 0.f);
        const float* base = Af + (size_t)gr * K + gk;
        if (gk + 4 <= K) {
          v = *(const float4*)base;
        } else {
          if (gk + 0 < K) v.x = base[0];
          if (gk + 1 < K) v.y = base[1];
          if (gk + 2 < K) v.z = base[2];
          if (gk + 3 < K) v.w = base[3];
        }
        arf[p] = v;
      }
    }
  };
  auto loadB = [&](int k0) {
#pragma unroll
    for (int p = 0; p < BN / 64; ++p) {
      int f = tid + p * 256;
      int n = f >> 2, c8 = f & 3;
      brr[p] = *(const short8*)(BT + (size_t)n * Kpad + k0 + c8 * 8);
    }
  };
  auto storeAB = [&]() {
    if (ABF16) {
      int row = tid >> 2, c8 = tid & 3;
      *reinterpret_cast<short8*>(&As[row * LW + c8 * 8]) = arh;
    } else {
#pragma unroll
      for (int p = 0; p < 2; ++p) {
        int f = tid + p * 256;
        int row = f >> 3, c4 = f & 7;
        unsigned a0 = (unsigned)f32_bf16(arf[p].x) | ((unsigned)f32_bf16(arf[p].y) << 16);
        unsigned a1 = (unsigned)f32_bf16(arf[p].z) | ((unsigned)f32_bf16(arf[p].w) << 16);
        *reinterpret_cast<uint2*>(&As[row * LW + c4 * 4]) = make_uint2(a0, a1);
      }
    }
#pragma unroll
    for (int p = 0; p < BN / 64; ++p) {
      int f = tid + p * 256;
      int n = f >> 2, c8 = f & 3;
      *reinterpret_cast<short8*>(&Bs[n * LW + c8 * 8]) = brr[p];
    }
  };

  loadA(0);
  loadB(0);
  for (int kt = 0; kt < nt; ++kt) {
    if (kt) __syncthreads();
    storeAB();
    __syncthreads();
    if (kt + 1 < nt) {
      loadA((kt + 1) * BK);
      loadB((kt + 1) * BK);
    }
    short8 af[FM], bf[FN];
#pragma unroll
    for (int i = 0; i < FM; ++i)
      af[i] = *reinterpret_cast<const short8*>(&As[(rowbase + i * 16 + lrow) * LW + lk * 8]);
#pragma unroll
    for (int j = 0; j < FN; ++j)
      bf[j] = *reinterpret_cast<const short8*>(&Bs[(colbase + j * 16 + lrow) * LW + lk * 8]);
#pragma unroll
    for (int i = 0; i < FM; ++i)
#pragma unroll
      for (int j = 0; j < FN; ++j)
        acc[i][j] = __builtin_amdgcn_mfma_f32_16x16x32_bf16(af[i], bf[j], acc[i][j], 0, 0, 0);
  }

  if (PRED) {
    float p0[4] = {0.f, 0.f, 0.f, 0.f}, p1[4] = {0.f, 0.f, 0.f, 0.f};
#pragma unroll
    for (int j = 0; j < FN; ++j) {
      int col = j * 16 + lrow;
      float w0 = Wp[col * 2], w1 = Wp[col * 2 + 1];
      float fb = fbias[col];
#pragma unroll
      for (int q = 0; q < 4; ++q) {
        float v = fmaxf(acc[0][j][q] + fb, 0.f);
        p0[q] += v * w0;
        p1[q] += v * w1;
      }
    }
#pragma unroll
    for (int o = 1; o < 16; o <<= 1) {
#pragma unroll
      for (int q = 0; q < 4; ++q) {
        p0[q] += __shfl_xor(p0[q], o);
        p1[q] += __shfl_xor(p1[q], o);
      }
    }
    if (lrow == 0) {
#pragma unroll
      for (int q = 0; q < 4; ++q) {
        int row = m0 + rowbase + lk * 4 + q;
        if (row < M) {
          pout[(size_t)row * 2 + 0] = p0[q] + bp[0];
          pout[(size_t)row * 2 + 1] = p1[q] + bp[1];
        }
      }
    }
  } else {
#pragma unroll
    for (int i = 0; i < FM; ++i) {
#pragma unroll
      for (int j = 0; j < FN; ++j) {
#pragma unroll
        for (int q = 0; q < 4; ++q) {
          int row = m0 + rowbase + i * 16 + lk * 4 + q;
          int col = colbase + j * 16 + lrow;
          if (row < M) C[(size_t)row * ldc + col] = f32_bf16(acc[i][j][q]);
        }
      }
    }
  }
}

// ---------------- mega kernel roles ----------------
struct EdgeArgs { const int* ei[3]; const float* ew[3]; };

struct MegaArgs {
  int nCount, nScatter, nG1, nG2, nFuse, nA128, nA64;
  // G1 slots (GXc blocks each)
  const float* g1A[3]; const unsigned short* g1B[3]; unsigned short* g1C[3];
  int g1K[3], g1Kp[3];
  // G2 slots
  const unsigned short* g2A[3]; const unsigned short* g2B[3]; unsigned short* g2C[3];
  // fuse+pred
  const unsigned short* fA; const unsigned short* fB;
  const float* fBias; const float* fWp; const float* fBp; float* fOut;
  // agg128 slots
  int aBr[3]; const unsigned short* aX[3]; const float* aBias[3]; unsigned short* aOut[3];
  // agg64 slots
  int bBr[3]; const unsigned short* bX[3]; const float* bBias[3]; unsigned short* bOut;
  // shared graph state
  EdgeArgs ea;
  ull* pcTot;          // [3*NN] (count<<32 | fix24 wsum)
  const int* off3;     // [3*NN]
  int2* csrW;          // [3*NE] {src, norm bits}
  const float* dinv3;  // [3*NN]
};

// count: LDS histogram per (branch, range); zero global atomics
__device__ void count_body(const MegaArgs& a, char* lds, int bx) {
  int b = bx / NR, r = bx - b * NR;
  int lo = r * RNG;
  int n = NN - lo;
  if (n > RNG) n = RNG;
  unsigned* cnt = (unsigned*)lds;            // [RNG]
  unsigned* wsum = (unsigned*)lds + RNG;     // [RNG]
  for (int j = threadIdx.x; j < RNG; j += 256) {
    cnt[j] = 0;
    wsum[j] = 0;
  }
  __syncthreads();
  const int* __restrict__ dstp = a.ea.ei[b] + NE;
  const float* __restrict__ ewp = a.ea.ew[b];
  for (int e = threadIdx.x; e < NE; e += 256) {
    unsigned dd = (unsigned)dstp[e] - (unsigned)lo;
    if (dd < (unsigned)n) {
      float w = ewp[e];
      atomicAdd(&cnt[dd], 1u);
      atomicAdd(&wsum[dd], (unsigned)(w * 16777216.0f));
    }
  }
  __syncthreads();
  for (int j = threadIdx.x; j < n; j += 256)
    a.pcTot[b * NN + lo + j] = ((ull)cnt[j] << 32) | wsum[j];
}

// scatter: LDS cursors from off3; csr writes land in a ~200KB window
__device__ void scatter_body(const MegaArgs& a, char* lds, int bx) {
  int b = bx / NR, r = bx - b * NR;
  int lo = r * RNG;
  int n = NN - lo;
  if (n > RNG) n = RNG;
  int* cur = (int*)lds;                      // [RNG]
  float* dv = (float*)((int*)lds + RNG);     // [RNG]
  const float* dinv = a.dinv3 + (size_t)b * NN;
  for (int j = threadIdx.x; j < n; j += 256) {
    cur[j] = a.off3[b * NN + lo + j];
    dv[j] = dinv[lo + j];
  }
  __syncthreads();
  const int* __restrict__ srcp = a.ea.ei[b];
  const int* __restrict__ dstp = srcp + NE;
  const float* __restrict__ ewp = a.ea.ew[b];
  int2* __restrict__ out = a.csrW + (size_t)b * NE;
  for (int e = threadIdx.x; e < NE; e += 256) {
    unsigned dd = (unsigned)dstp[e] - (unsigned)lo;
    if (dd < (unsigned)n) {
      int s = srcp[e];
      float w = ewp[e];
      int pos = atomicAdd(&cur[dd], 1);
      float cw = dinv[s] * w * dv[dd];
      out[pos] = make_int2(s, __float_as_int(cw));
    }
  }
}

__device__ void agg128_body(const MegaArgs& a, int slot, int t) {
  int i = (t << 2) + ((int)threadIdx.x >> 6);
  if (i >= NN) return;
  int lane = threadIdx.x & 63;
  int br = a.aBr[slot];
  const unsigned short* x = a.aX[slot];
  float di = a.dinv3[(size_t)br * NN + i];
  unsigned sv = *(const unsigned*)(x + (size_t)i * 128 + lane * 2);
  float w0 = di * di;
  float acc0 = bf_lo(sv) * w0, acc1 = bf_hi(sv) * w0;
  int cnt = (int)(a.pcTot[(size_t)br * NN + i] >> 32);
  const int2* cp = a.csrW + (size_t)br * NE + a.off3[br * NN + i];
  for (int t2 = 0; t2 < cnt; ++t2) {
    int2 sl = cp[t2];
    float wt = __int_as_float(sl.y);
    unsigned v = *(const unsigned*)(x + (size_t)sl.x * 128 + lane * 2);
    acc0 += bf_lo(v) * wt;
    acc1 += bf_hi(v) * wt;
  }
  acc0 = fmaxf(acc0 + a.aBias[slot][lane * 2], 0.f);
  acc1 = fmaxf(acc1 + a.aBias[slot][lane * 2 + 1], 0.f);
  unsigned o = (unsigned)f32_bf16(acc0) | ((unsigned)f32_bf16(acc1) << 16);
  *(unsigned*)(a.aOut[slot] + (size_t)i * 128 + lane * 2) = o;
}

__device__ void agg64_body(const MegaArgs& a, int slot, int t) {
  int i = (t << 2) + ((int)threadIdx.x >> 6);
  if (i >= NN) return;
  int lane = threadIdx.x & 63;
  int half = lane >> 5, l2 = (lane & 31) * 2;
  int br = a.bBr[slot];
  const unsigned short* x = a.bX[slot];
  float di = a.dinv3[(size_t)br * NN + i];
  float acc0 = 0.f, acc1 = 0.f;
  if (half == 0) {
    unsigned sv = *(const unsigned*)(x + (size_t)i * 64 + l2);
    float w0 = di * di;
    acc0 = bf_lo(sv) * w0;
    acc1 = bf_hi(sv) * w0;
  }
  int cnt = (int)(a.pcTot[(size_t)br * NN + i] >> 32);
  const int2* cp = a.csrW + (size_t)br * NE + a.off3[br * NN + i];
  for (int t2 = half; t2 < cnt; t2 += 2) {
    int2 sl = cp[t2];
    float wt = __int_as_float(sl.y);
    unsigned v = *(const unsigned*)(x + (size_t)sl.x * 64 + l2);
    acc0 += bf_lo(v) * wt;
    acc1 += bf_hi(v) * wt;
  }
  acc0 += __shfl_xor(acc0, 32);
  acc1 += __shfl_xor(acc1, 32);
  if (half == 0) {
    acc0 = fmaxf(acc0 + a.bBias[slot][l2], 0.f);
    acc1 = fmaxf(acc1 + a.bBias[slot][l2 + 1], 0.f);
    unsigned o = (unsigned)f32_bf16(acc0) | ((unsigned)f32_bf16(acc1) << 16);
    *(unsigned*)(a.bOut + (size_t)i * 192 + br * 64 + l2) = o;
  }
}

__global__ __launch_bounds__(256) void mega_kernel(MegaArgs a) {
  extern __shared__ char lds[];
  int bx = blockIdx.x;
  if (bx < a.nCount) {
    count_body(a, lds, bx);
    return;
  }
  bx -= a.nCount;
  if (bx < a.nScatter) {
    scatter_body(a, lds, bx);
    return;
  }
  bx -= a.nScatter;
  if (bx < a.nG1) {
    int slot = bx / GXc, b2 = bx - slot * GXc;
    gemm_body<128, false, false>(lds, a.g1A[slot], a.g1B[slot], a.g1C[slot], NN, a.g1K[slot],
                                 a.g1Kp[slot], 128, nullptr, nullptr, nullptr, nullptr, b2);
    return;
  }
  bx -= a.nG1;
  if (bx < a.nG2) {
    int slot = bx / GXc, b2 = bx - slot * GXc;
    gemm_body<64, true, false>(lds, a.g2A[slot], a.g2B[slot], a.g2C[slot], NN, 128, 128, 64,
                               nullptr, nullptr, nullptr, nullptr, b2);
    return;
  }
  bx -= a.nG2;
  if (bx < a.nFuse) {
    gemm_body<64, true, true>(lds, a.fA, a.fB, nullptr, NN, 192, 192, 0, a.fBias, a.fWp, a.fBp,
                              a.fOut, bx);
    return;
  }
  bx -= a.nFuse;
  if (bx < a.nA128) {
    int slot = bx / ABc;
    agg128_body(a, slot, bx - slot * ABc);
    return;
  }
  bx -= a.nA128;
  int slot = bx / ABc;
  agg64_body(a, slot, bx - slot * ABc);
}

// ---------------- scans over pcTot ----------------
__global__ void scan1_kernel(const ull* __restrict__ pcTot, int* __restrict__ partial3,
                             int* __restrict__ bsums3, int n, int bpb) {
  __shared__ int sd[256];
  int b = blockIdx.x / bpb, blk = blockIdx.x % bpb;
  int i = blk * 256 + threadIdx.x;
  int v = (i < n) ? (int)(pcTot[b * NN + i] >> 32) : 0;
  sd[threadIdx.x] = v;
  __syncthreads();
  for (int o = 1; o < 256; o <<= 1) {
    int t = (threadIdx.x >= o) ? sd[threadIdx.x - o] : 0;
    __syncthreads();
    sd[threadIdx.x] += t;
    __syncthreads();
  }
  if (i < n) partial3[b * NN + i] = sd[threadIdx.x];
  if (threadIdx.x == 255) bsums3[b * 256 + blk] = sd[255];
}

__global__ void scan2_kernel(int* __restrict__ bsums3, int nb) {
  __shared__ int sd[256];
  int b = blockIdx.x;
  int v = (threadIdx.x < nb) ? bsums3[b * 256 + threadIdx.x] : 0;
  sd[threadIdx.x] = v;
  __syncthreads();
  for (int o = 1; o < 256; o <<= 1) {
    int t = (threadIdx.x >= o) ? sd[threadIdx.x - o] : 0;
    __syncthreads();
    sd[threadIdx.x] += t;
    __syncthreads();
  }
  if (threadIdx.x < nb) bsums3[b * 256 + threadIdx.x] = sd[threadIdx.x] - v;
}

__global__ void scan3_kernel(const ull* __restrict__ pcTot, const int* __restrict__ partial3,
                             const int* __restrict__ bsums3, int* __restrict__ off3,
                             float* __restrict__ dinv3, int n, int bpb) {
  int b = blockIdx.x / bpb, blk = blockIdx.x % bpb;
  int i = blk * 256 + threadIdx.x;
  if (i >= n) return;
  ull v = pcTot[b * NN + i];
  int c = (int)(v >> 32);
  off3[b * NN + i] = partial3[b * NN + i] - c + bsums3[b * 256 + blk];
  float deg = (float)(unsigned)(v & 0xFFFFFFFFull) * (1.0f / 16777216.0f) + 1.0f;
  dinv3[b * NN + i] = rsqrtf(deg);
}

extern "C" void kernel_launch(void* const* d_in, const int* in_sizes, int n_in, void* d_out,
                              int out_size, void* d_ws, size_t ws_size, hipStream_t stream) {
  const int Ds[3] = {1000, 1000, 500};
  const int H1 = 128, H2 = 64;

  char* p = (char*)d_ws;
  auto carve = [&](size_t bytes) {
    void* r = (void*)p;
    p += (bytes + 255) & ~(size_t)255;
    return r;
  };

  unsigned short* w1t[3];
  int kpad1[3];
  for (int b = 0; b < 3; ++b) {
    kpad1[b] = (Ds[b] + 31) & ~31;
    w1t[b] = (unsigned short*)carve((size_t)H1 * kpad1[b] * 2);
  }
  unsigned short* w2t[3];
  for (int b = 0; b < 3; ++b) w2t[b] = (unsigned short*)carve((size_t)H2 * 128 * 2);
  unsigned short* wft = (unsigned short*)carve((size_t)H2 * 192 * 2);

  ull* pcTot = (ull*)carve((size_t)3 * NN * 8);
  float* dinv3 = (float*)carve((size_t)3 * NN * 4);
  int* partial3 = (int*)carve((size_t)3 * NN * 4);
  int* bsums3 = (int*)carve((size_t)3 * 256 * 4);
  int* off3 = (int*)carve((size_t)3 * NN * 4);
  int2* csr = (int2*)carve((size_t)3 * NE * 8);
  unsigned short* x1[3], *h1[3], *x2[3];
  for (int b = 0; b < 3; ++b) x1[b] = (unsigned short*)carve((size_t)NN * 128 * 2);
  for (int b = 0; b < 3; ++b) h1[b] = (unsigned short*)carve((size_t)NN * 128 * 2);
  for (int b = 0; b < 3; ++b) x2[b] = (unsigned short*)carve((size_t)NN * 64 * 2);
  unsigned short* comb = (unsigned short*)carve((size_t)NN * 192 * 2);

  const int nb = (NN + 255) / 256;  // 196

  // ---- transposes ----
  TransArgs ta;
  int base = 0;
  const float* wsrc[7] = {(const float*)d_in[3],  (const float*)d_in[10], (const float*)d_in[17],
                          (const float*)d_in[5],  (const float*)d_in[12], (const float*)d_in[19],
                          (const float*)d_in[21]};
  unsigned short* wdst[7] = {w1t[0], w1t[1], w1t[2], w2t[0], w2t[1], w2t[2], wft};
  int wK[7] = {1000, 1000, 500, 128, 128, 128, 192};
  int wN[7] = {128, 128, 128, 64, 64, 64, 64};
  int wKp[7] = {1024, 1024, 512, 128, 128, 128, 192};
  for (int s = 0; s < 7; ++s) {
    ta.d[s] = {wsrc[s], wdst[s], wK[s], wN[s], wKp[s], base};
    base += wN[s] * wKp[s];
  }
  ta.total = base;
  transpose_all_kernel<<<(base + 255) / 256, 256, 0, stream>>>(ta);

  // ---- base args ----
  MegaArgs baseArgs;
  memset(&baseArgs, 0, sizeof(baseArgs));
  for (int b = 0; b < 3; ++b) {
    baseArgs.ea.ei[b] = (const int*)d_in[b * 7 + 1];
    baseArgs.ea.ew[b] = (const float*)d_in[b * 7 + 2];
  }
  baseArgs.pcTot = pcTot;
  baseArgs.off3 = off3;
  baseArgs.csrW = csr;
  baseArgs.dinv3 = dinv3;

  auto launch = [&](MegaArgs& m, size_t ldsb) {
    int g = m.nCount + m.nScatter + m.nG1 + m.nG2 + m.nFuse + m.nA128 + m.nA64;
    mega_kernel<<<g, 256, ldsb, stream>>>(m);
  };

  MegaArgs m;

  // L2: count (75 LDS-hist blocks) + GEMM1 x3
  m = baseArgs;
  m.nCount = 3 * NR;
  for (int b = 0; b < 3; ++b) {
    m.g1A[b] = (const float*)d_in[b * 7 + 0];
    m.g1B[b] = w1t[b];
    m.g1C[b] = x1[b];
    m.g1K[b] = Ds[b];
    m.g1Kp[b] = kpad1[b];
  }
  m.nG1 = 3 * GXc;
  launch(m, 16384);

  // L3-L5: scans (+dinv)
  scan1_kernel<<<3 * nb, 256, 0, stream>>>(pcTot, partial3, bsums3, NN, nb);
  scan2_kernel<<<3, 256, 0, stream>>>(bsums3, nb);
  scan3_kernel<<<3 * nb, 256, 0, stream>>>(pcTot, partial3, bsums3, off3, dinv3, NN, nb);

  // L6: scatter (75 blocks)
  m = baseArgs;
  m.nScatter = 3 * NR;
  launch(m, 16384);

  // L7: agg128 x3
  m = baseArgs;
  m.nA128 = 3 * ABc;
  for (int b = 0; b < 3; ++b) {
    m.aBr[b] = b;
    m.aX[b] = x1[b];
    m.aBias[b] = (const float*)d_in[b * 7 + 4];
    m.aOut[b] = h1[b];
  }
  launch(m, 0);

  // L8: gemm2 x3
  m = baseArgs;
  m.nG2 = 3 * GXc;
  for (int b = 0; b < 3; ++b) {
    m.g2A[b] = h1[b];
    m.g2B[b] = w2t[b];
    m.g2C[b] = x2[b];
  }
  launch(m, 10240);

  // L9: agg64 x3
  m = baseArgs;
  m.nA64 = 3 * ABc;
  for (int b = 0; b < 3; ++b) {
    m.bBr[b] = b;
    m.bX[b] = x2[b];
    m.bBias[b] = (const float*)d_in[b * 7 + 6];
  }
  m.bOut = comb;
  launch(m, 0);

  // L10: fuse + pred
  m = baseArgs;
  m.nFuse = GXc;
  m.fA = comb;
  m.fB = wft;
  m.fBias = (const float*)d_in[22];
  m.fWp = (const float*)d_in[23];
  m.fBp = (const float*)d_in[24];
  m.fOut = (float*)d_out;
  launch(m, 10240);
}

// Round 7
// 604.465 us; speedup vs baseline: 5.8083x; 5.8083x over previous
//
#include <hip/hip_runtime.h>
#include <hip/hip_bf16.h>
#include <string.h>

typedef __attribute__((ext_vector_type(8))) short short8;
typedef __attribute__((ext_vector_type(4))) float f32x4;
typedef unsigned long long ull;

#define NN 50000
#define NE 600000
#define GXc 782    // ceil(50000/64)
#define ABc 12500  // ceil(50000/4)
#define NCB 2048   // count-role virtual blocks

__device__ __forceinline__ unsigned short f32_bf16(float f) {
  unsigned u = __float_as_uint(f);
  unsigned r = u + 0x7FFFu + ((u >> 16) & 1u);
  return (unsigned short)(r >> 16);
}
__device__ __forceinline__ float bf_lo(unsigned v) { return __uint_as_float(v << 16); }
__device__ __forceinline__ float bf_hi(unsigned v) { return __uint_as_float(v & 0xFFFF0000u); }

// ---------------- fused transpose of all 7 weights ----------------
struct TransDesc { const float* src; unsigned short* dst; int K, Nn, Kpad, base; };
struct TransArgs { TransDesc d[7]; int total; };

__global__ void transpose_all_kernel(TransArgs a) {
  int idx = blockIdx.x * 256 + threadIdx.x;
  if (idx >= a.total) return;
  int s = 0;
#pragma unroll
  for (int q = 1; q < 7; ++q)
    if (idx >= a.d[q].base) s = q;
  TransDesc t = a.d[s];
  int off = idx - t.base;
  int n = off / t.Kpad, k = off % t.Kpad;
  float v = (k < t.K) ? t.src[(size_t)k * t.Nn + n] : 0.f;
  t.dst[off] = f32_bf16(v);
}

// ---------------- GEMM body (bf16 MFMA, BM=64, register prefetch, dynamic LDS) ----
template <int BN, bool ABF16, bool PRED>
__device__ __forceinline__ void gemm_body(char* ldsraw, const void* __restrict__ Av,
                                          const unsigned short* __restrict__ BT,
                                          unsigned short* __restrict__ C, int M, int K, int Kpad,
                                          int ldc, const float* fbias, const float* Wp,
                                          const float* bp, float* pout, int bx) {
  constexpr int BM = 64, BK = 32, LW = BK + 8;
  unsigned short* As = (unsigned short*)ldsraw;
  unsigned short* Bs = As + BM * LW;
  const int tid = threadIdx.x;
  const int m0 = bx * BM;
  const int wid = tid >> 6, lane = tid & 63;
  constexpr int WC = (BN == 128) ? 2 : 1;
  constexpr int WTM = (BN == 128) ? 32 : 16;
  constexpr int FM = WTM / 16;
  constexpr int FN = 4;
  const int wr = wid / WC, wc = wid % WC;
  const int rowbase = wr * WTM, colbase = wc * 64;
  const int lrow = lane & 15, lk = lane >> 4;

  const float* Af = (const float*)Av;
  const unsigned short* Ah = (const unsigned short*)Av;

  f32x4 acc[FM][FN] = {};
  float4 arf[2];
  short8 arh;
  short8 brr[BN / 64];

  const int nt = Kpad / BK;

  auto loadA = [&](int k0) {
    if (ABF16) {
      int row = tid >> 2, c8 = tid & 3;
      int gr = m0 + row;
      if (gr >= M) gr = M - 1;
      arh = *(const short8*)(Ah + (size_t)gr * K + k0 + c8 * 8);
    } else {
#pragma unroll
      for (int p = 0; p < 2; ++p) {
        int f = tid + p * 256;
        int row = f >> 3, c4 = f & 7;
        int gr = m0 + row;
        if (gr >= M) gr = M - 1;
        int gk = k0 + c4 * 4;
        float4 v = make_float4(0.f, 0.f, 0.f, 0.f);
        const float* base = Af + (size_t)gr * K + gk;
        if (gk + 4 <= K) {
          v = *(const float4*)base;
        } else {
          if (gk + 0 < K) v.x = base[0];
          if (gk + 1 < K) v.y = base[1];
          if (gk + 2 < K) v.z = base[2];
          if (gk + 3 < K) v.w = base[3];
        }
        arf[p] = v;
      }
    }
  };
  auto loadB = [&](int k0) {
#pragma unroll
    for (int p = 0; p < BN / 64; ++p) {
      int f = tid + p * 256;
      int n = f >> 2, c8 = f & 3;
      brr[p] = *(const short8*)(BT + (size_t)n * Kpad + k0 + c8 * 8);
    }
  };
  auto storeAB = [&]() {
    if (ABF16) {
      int row = tid >> 2, c8 = tid & 3;
      *reinterpret_cast<short8*>(&As[row * LW + c8 * 8]) = arh;
    } else {
#pragma unroll
      for (int p = 0; p < 2; ++p) {
        int f = tid + p * 256;
        int row = f >> 3, c4 = f & 7;
        unsigned a0 = (unsigned)f32_bf16(arf[p].x) | ((unsigned)f32_bf16(arf[p].y) << 16);
        unsigned a1 = (unsigned)f32_bf16(arf[p].z) | ((unsigned)f32_bf16(arf[p].w) << 16);
        *reinterpret_cast<uint2*>(&As[row * LW + c4 * 4]) = make_uint2(a0, a1);
      }
    }
#pragma unroll
    for (int p = 0; p < BN / 64; ++p) {
      int f = tid + p * 256;
      int n = f >> 2, c8 = f & 3;
      *reinterpret_cast<short8*>(&Bs[n * LW + c8 * 8]) = brr[p];
    }
  };

  loadA(0);
  loadB(0);
  for (int kt = 0; kt < nt; ++kt) {
    if (kt) __syncthreads();
    storeAB();
    __syncthreads();
    if (kt + 1 < nt) {
      loadA((kt + 1) * BK);
      loadB((kt + 1) * BK);
    }
    short8 af[FM], bf[FN];
#pragma unroll
    for (int i = 0; i < FM; ++i)
      af[i] = *reinterpret_cast<const short8*>(&As[(rowbase + i * 16 + lrow) * LW + lk * 8]);
#pragma unroll
    for (int j = 0; j < FN; ++j)
      bf[j] = *reinterpret_cast<const short8*>(&Bs[(colbase + j * 16 + lrow) * LW + lk * 8]);
#pragma unroll
    for (int i = 0; i < FM; ++i)
#pragma unroll
      for (int j = 0; j < FN; ++j)
        acc[i][j] = __builtin_amdgcn_mfma_f32_16x16x32_bf16(af[i], bf[j], acc[i][j], 0, 0, 0);
  }

  if (PRED) {
    float p0[4] = {0.f, 0.f, 0.f, 0.f}, p1[4] = {0.f, 0.f, 0.f, 0.f};
#pragma unroll
    for (int j = 0; j < FN; ++j) {
      int col = j * 16 + lrow;
      float w0 = Wp[col * 2], w1 = Wp[col * 2 + 1];
      float fb = fbias[col];
#pragma unroll
      for (int q = 0; q < 4; ++q) {
        float v = fmaxf(acc[0][j][q] + fb, 0.f);
        p0[q] += v * w0;
        p1[q] += v * w1;
      }
    }
#pragma unroll
    for (int o = 1; o < 16; o <<= 1) {
#pragma unroll
      for (int q = 0; q < 4; ++q) {
        p0[q] += __shfl_xor(p0[q], o);
        p1[q] += __shfl_xor(p1[q], o);
      }
    }
    if (lrow == 0) {
#pragma unroll
      for (int q = 0; q < 4; ++q) {
        int row = m0 + rowbase + lk * 4 + q;
        if (row < M) {
          pout[(size_t)row * 2 + 0] = p0[q] + bp[0];
          pout[(size_t)row * 2 + 1] = p1[q] + bp[1];
        }
      }
    }
  } else {
#pragma unroll
    for (int i = 0; i < FM; ++i) {
#pragma unroll
      for (int j = 0; j < FN; ++j) {
#pragma unroll
        for (int q = 0; q < 4; ++q) {
          int row = m0 + rowbase + i * 16 + lk * 4 + q;
          int col = colbase + j * 16 + lrow;
          if (row < M) C[(size_t)row * ldc + col] = f32_bf16(acc[i][j][q]);
        }
      }
    }
  }
}

// ---------------- megaA: interleaved count (atomic rank) + GEMM1 x3 ----------------
struct MegaAArgs {
  const int* ei[3];
  const float* ew[3];
  ull* pc;
  unsigned short* rank;
  const float* g1A[3];
  const unsigned short* g1B[3];
  unsigned short* g1C[3];
  int g1K[3], g1Kp[3];
};

__global__ __launch_bounds__(256) void megaA_kernel(MegaAArgs a) {
  extern __shared__ char lds[];
  int bx = blockIdx.x;
  int gid = -1, cid = -1;
  if (bx < 2 * NCB) {
    if (bx & 1) cid = bx >> 1;
    else gid = bx >> 1;
  } else {
    gid = NCB + (bx - 2 * NCB);
  }
  if (cid >= 0) {
    const int stride = NCB * 256;
    for (int idx = cid * 256 + (int)threadIdx.x; idx < 3 * NE; idx += stride) {
      int b = (idx >= 2 * NE) ? 2 : ((idx >= NE) ? 1 : 0);
      int e = idx - b * NE;
      int d = a.ei[b][NE + e];
      float w = a.ew[b][e];
      ull pkt = (1ull << 32) | (ull)(unsigned)(w * 16777216.0f);
      ull old = atomicAdd(&a.pc[b * NN + d], pkt);
      a.rank[idx] = (unsigned short)(old >> 32);
    }
  } else {
    int slot = gid / GXc, b2 = gid - slot * GXc;
    gemm_body<128, false, false>(lds, a.g1A[slot], a.g1B[slot], a.g1C[slot], NN, a.g1K[slot],
                                 a.g1Kp[slot], 128, nullptr, nullptr, nullptr, nullptr, b2);
  }
}

// ---------------- scans over pc ----------------
__global__ void scan1_kernel(const ull* __restrict__ pc, int* __restrict__ partial3,
                             int* __restrict__ bsums3, int n, int bpb) {
  __shared__ int sd[256];
  int b = blockIdx.x / bpb, blk = blockIdx.x % bpb;
  int i = blk * 256 + threadIdx.x;
  int v = (i < n) ? (int)(pc[b * NN + i] >> 32) : 0;
  sd[threadIdx.x] = v;
  __syncthreads();
  for (int o = 1; o < 256; o <<= 1) {
    int t = (threadIdx.x >= o) ? sd[threadIdx.x - o] : 0;
    __syncthreads();
    sd[threadIdx.x] += t;
    __syncthreads();
  }
  if (i < n) partial3[b * NN + i] = sd[threadIdx.x];
  if (threadIdx.x == 255) bsums3[b * 256 + blk] = sd[255];
}

__global__ void scan2_kernel(int* __restrict__ bsums3, int nb) {
  __shared__ int sd[256];
  int b = blockIdx.x;
  int v = (threadIdx.x < nb) ? bsums3[b * 256 + threadIdx.x] : 0;
  sd[threadIdx.x] = v;
  __syncthreads();
  for (int o = 1; o < 256; o <<= 1) {
    int t = (threadIdx.x >= o) ? sd[threadIdx.x - o] : 0;
    __syncthreads();
    sd[threadIdx.x] += t;
    __syncthreads();
  }
  if (threadIdx.x < nb) bsums3[b * 256 + threadIdx.x] = sd[threadIdx.x] - v;
}

__global__ void scan3_kernel(const ull* __restrict__ pc, const int* __restrict__ partial3,
                             const int* __restrict__ bsums3, int* __restrict__ off3,
                             float* __restrict__ dinv3, int n, int bpb) {
  int b = blockIdx.x / bpb, blk = blockIdx.x % bpb;
  int i = blk * 256 + threadIdx.x;
  if (i >= n) return;
  ull v = pc[b * NN + i];
  int c = (int)(v >> 32);
  off3[b * NN + i] = partial3[b * NN + i] - c + bsums3[b * 256 + blk];
  float deg = (float)(unsigned)(v & 0xFFFFFFFFull) * (1.0f / 16777216.0f) + 1.0f;
  dinv3[b * NN + i] = rsqrtf(deg);
}

// ---------------- scatter (atomic-free, rank-based) ----------------
struct ScatArgs {
  const int* ei[3];
  const float* ew[3];
  const unsigned short* rank;
  const int* off3;
  const float* dinv3;
  int2* csr;
};

__global__ __launch_bounds__(256) void scatter_kernel(ScatArgs a) {
  const int stride = gridDim.x * 256;
  for (int idx = blockIdx.x * 256 + (int)threadIdx.x; idx < 3 * NE; idx += stride) {
    int b = (idx >= 2 * NE) ? 2 : ((idx >= NE) ? 1 : 0);
    int e = idx - b * NE;
    int d = a.ei[b][NE + e], s = a.ei[b][e];
    float w = a.ew[b][e];
    int t = a.off3[b * NN + d] + (int)a.rank[idx];
    float cw = a.dinv3[b * NN + s] * w * a.dinv3[b * NN + d];
    a.csr[(size_t)b * NE + t] = make_int2(s, __float_as_int(cw));
  }
}

// ---------------- agg128 x3 (unroll-2) ----------------
struct AggArgs {
  const unsigned short* x[3];
  const float* bias[3];
  unsigned short* out[3];  // agg64: out[0] = comb base
  const float* dinv3;
  const ull* pc;
  const int* off3;
  const int2* csr;
};

__global__ __launch_bounds__(256) void agg128x3_kernel(AggArgs a) {
  int bx = blockIdx.x;
  int slot = bx / ABc, t = bx - slot * ABc;
  int i = (t << 2) + ((int)threadIdx.x >> 6);
  if (i >= NN) return;
  int lane = threadIdx.x & 63;
  const unsigned short* x = a.x[slot];
  float di = a.dinv3[(size_t)slot * NN + i];
  unsigned sv = *(const unsigned*)(x + (size_t)i * 128 + lane * 2);
  float w0s = di * di;
  float acc0 = bf_lo(sv) * w0s, acc1 = bf_hi(sv) * w0s;
  int cnt = (int)(a.pc[(size_t)slot * NN + i] >> 32);
  const int2* cp = a.csr + (size_t)slot * NE + a.off3[slot * NN + i];
  int t2 = 0;
  for (; t2 + 2 <= cnt; t2 += 2) {
    int2 s0 = cp[t2], s1 = cp[t2 + 1];
    unsigned v0 = *(const unsigned*)(x + (size_t)s0.x * 128 + lane * 2);
    unsigned v1 = *(const unsigned*)(x + (size_t)s1.x * 128 + lane * 2);
    float wa = __int_as_float(s0.y), wb = __int_as_float(s1.y);
    acc0 += bf_lo(v0) * wa + bf_lo(v1) * wb;
    acc1 += bf_hi(v0) * wa + bf_hi(v1) * wb;
  }
  if (t2 < cnt) {
    int2 s0 = cp[t2];
    unsigned v0 = *(const unsigned*)(x + (size_t)s0.x * 128 + lane * 2);
    float wa = __int_as_float(s0.y);
    acc0 += bf_lo(v0) * wa;
    acc1 += bf_hi(v0) * wa;
  }
  acc0 = fmaxf(acc0 + a.bias[slot][lane * 2], 0.f);
  acc1 = fmaxf(acc1 + a.bias[slot][lane * 2 + 1], 0.f);
  unsigned o = (unsigned)f32_bf16(acc0) | ((unsigned)f32_bf16(acc1) << 16);
  *(unsigned*)(a.out[slot] + (size_t)i * 128 + lane * 2) = o;
}

// ---------------- agg64 x3 (writes comb columns) ----------------
__global__ __launch_bounds__(256) void agg64x3_kernel(AggArgs a) {
  int bx = blockIdx.x;
  int slot = bx / ABc, t = bx - slot * ABc;
  int i = (t << 2) + ((int)threadIdx.x >> 6);
  if (i >= NN) return;
  int lane = threadIdx.x & 63;
  int half = lane >> 5, l2 = (lane & 31) * 2;
  const unsigned short* x = a.x[slot];
  float di = a.dinv3[(size_t)slot * NN + i];
  float acc0 = 0.f, acc1 = 0.f;
  if (half == 0) {
    unsigned sv = *(const unsigned*)(x + (size_t)i * 64 + l2);
    float w0s = di * di;
    acc0 = bf_lo(sv) * w0s;
    acc1 = bf_hi(sv) * w0s;
  }
  int cnt = (int)(a.pc[(size_t)slot * NN + i] >> 32);
  const int2* cp = a.csr + (size_t)slot * NE + a.off3[slot * NN + i];
  for (int t2 = half; t2 < cnt; t2 += 2) {
    int2 sl = cp[t2];
    float wt = __int_as_float(sl.y);
    unsigned v = *(const unsigned*)(x + (size_t)sl.x * 64 + l2);
    acc0 += bf_lo(v) * wt;
    acc1 += bf_hi(v) * wt;
  }
  acc0 += __shfl_xor(acc0, 32);
  acc1 += __shfl_xor(acc1, 32);
  if (half == 0) {
    acc0 = fmaxf(acc0 + a.bias[slot][l2], 0.f);
    acc1 = fmaxf(acc1 + a.bias[slot][l2 + 1], 0.f);
    unsigned o = (unsigned)f32_bf16(acc0) | ((unsigned)f32_bf16(acc1) << 16);
    *(unsigned*)(a.out[0] + (size_t)i * 192 + slot * 64 + l2) = o;
  }
}

// ---------------- gemm2 x3 ----------------
struct G2Args {
  const unsigned short* A[3];
  const unsigned short* B[3];
  unsigned short* C[3];
};

__global__ __launch_bounds__(256) void gemm2x3_kernel(G2Args a) {
  extern __shared__ char lds[];
  int slot = blockIdx.x / GXc, b2 = blockIdx.x - slot * GXc;
  gemm_body<64, true, false>(lds, a.A[slot], a.B[slot], a.C[slot], NN, 128, 128, 64, nullptr,
                             nullptr, nullptr, nullptr, b2);
}

// ---------------- fuse + pred ----------------
__global__ __launch_bounds__(256) void fuse_kernel(const unsigned short* __restrict__ comb,
                                                   const unsigned short* __restrict__ wft,
                                                   const float* __restrict__ fb,
                                                   const float* __restrict__ wp,
                                                   const float* __restrict__ bp,
                                                   float* __restrict__ out) {
  extern __shared__ char lds[];
  gemm_body<64, true, true>(lds, comb, wft, nullptr, NN, 192, 192, 0, fb, wp, bp, out,
                            blockIdx.x);
}

extern "C" void kernel_launch(void* const* d_in, const int* in_sizes, int n_in, void* d_out,
                              int out_size, void* d_ws, size_t ws_size, hipStream_t stream) {
  const int Ds[3] = {1000, 1000, 500};
  const int H1 = 128, H2 = 64;

  char* p = (char*)d_ws;
  auto carve = [&](size_t bytes) {
    void* r = (void*)p;
    p += (bytes + 255) & ~(size_t)255;
    return r;
  };

  unsigned short* w1t[3];
  int kpad1[3];
  for (int b = 0; b < 3; ++b) {
    kpad1[b] = (Ds[b] + 31) & ~31;
    w1t[b] = (unsigned short*)carve((size_t)H1 * kpad1[b] * 2);
  }
  unsigned short* w2t[3];
  for (int b = 0; b < 3; ++b) w2t[b] = (unsigned short*)carve((size_t)H2 * 128 * 2);
  unsigned short* wft = (unsigned short*)carve((size_t)H2 * 192 * 2);

  ull* pc = (ull*)carve((size_t)3 * NN * 8);
  float* dinv3 = (float*)carve((size_t)3 * NN * 4);
  int* partial3 = (int*)carve((size_t)3 * NN * 4);
  int* bsums3 = (int*)carve((size_t)3 * 256 * 4);
  int* off3 = (int*)carve((size_t)3 * NN * 4);
  unsigned short* rank = (unsigned short*)carve((size_t)3 * NE * 2);
  int2* csr = (int2*)carve((size_t)3 * NE * 8);
  unsigned short *x1[3], *h1[3], *x2[3];
  for (int b = 0; b < 3; ++b) x1[b] = (unsigned short*)carve((size_t)NN * 128 * 2);
  for (int b = 0; b < 3; ++b) h1[b] = (unsigned short*)carve((size_t)NN * 128 * 2);
  for (int b = 0; b < 3; ++b) x2[b] = (unsigned short*)carve((size_t)NN * 64 * 2);
  unsigned short* comb = (unsigned short*)carve((size_t)NN * 192 * 2);

  const int nb = (NN + 255) / 256;  // 196

  // ---- transposes ----
  TransArgs ta;
  int base = 0;
  const float* wsrc[7] = {(const float*)d_in[3],  (const float*)d_in[10], (const float*)d_in[17],
                          (const float*)d_in[5],  (const float*)d_in[12], (const float*)d_in[19],
                          (const float*)d_in[21]};
  unsigned short* wdst[7] = {w1t[0], w1t[1], w1t[2], w2t[0], w2t[1], w2t[2], wft};
  int wK[7] = {1000, 1000, 500, 128, 128, 128, 192};
  int wN[7] = {128, 128, 128, 64, 64, 64, 64};
  int wKp[7] = {1024, 1024, 512, 128, 128, 128, 192};
  for (int s = 0; s < 7; ++s) {
    ta.d[s] = {wsrc[s], wdst[s], wK[s], wN[s], wKp[s], base};
    base += wN[s] * wKp[s];
  }
  ta.total = base;
  transpose_all_kernel<<<(base + 255) / 256, 256, 0, stream>>>(ta);
  hipMemsetAsync(pc, 0, (size_t)3 * NN * 8, stream);

  // ---- megaA: interleaved count + GEMM1 x3 ----
  MegaAArgs ma;
  for (int b = 0; b < 3; ++b) {
    ma.ei[b] = (const int*)d_in[b * 7 + 1];
    ma.ew[b] = (const float*)d_in[b * 7 + 2];
    ma.g1A[b] = (const float*)d_in[b * 7 + 0];
    ma.g1B[b] = w1t[b];
    ma.g1C[b] = x1[b];
    ma.g1K[b] = Ds[b];
    ma.g1Kp[b] = kpad1[b];
  }
  ma.pc = pc;
  ma.rank = rank;
  const int megaGrid = 2 * NCB + (3 * GXc - NCB);  // 4096 + 298 = 4394
  megaA_kernel<<<megaGrid, 256, 15360, stream>>>(ma);

  // ---- scans ----
  scan1_kernel<<<3 * nb, 256, 0, stream>>>(pc, partial3, bsums3, NN, nb);
  scan2_kernel<<<3, 256, 0, stream>>>(bsums3, nb);
  scan3_kernel<<<3 * nb, 256, 0, stream>>>(pc, partial3, bsums3, off3, dinv3, NN, nb);

  // ---- scatter (no atomics) ----
  ScatArgs sa;
  for (int b = 0; b < 3; ++b) {
    sa.ei[b] = (const int*)d_in[b * 7 + 1];
    sa.ew[b] = (const float*)d_in[b * 7 + 2];
  }
  sa.rank = rank;
  sa.off3 = off3;
  sa.dinv3 = dinv3;
  sa.csr = csr;
  scatter_kernel<<<2048, 256, 0, stream>>>(sa);

  // ---- agg128 x3 ----
  AggArgs aa;
  for (int b = 0; b < 3; ++b) {
    aa.x[b] = x1[b];
    aa.bias[b] = (const float*)d_in[b * 7 + 4];
    aa.out[b] = h1[b];
  }
  aa.dinv3 = dinv3;
  aa.pc = pc;
  aa.off3 = off3;
  aa.csr = csr;
  agg128x3_kernel<<<3 * ABc, 256, 0, stream>>>(aa);

  // ---- gemm2 x3 ----
  G2Args g2;
  for (int b = 0; b < 3; ++b) {
    g2.A[b] = h1[b];
    g2.B[b] = w2t[b];
    g2.C[b] = x2[b];
  }
  gemm2x3_kernel<<<3 * GXc, 256, 10240, stream>>>(g2);

  // ---- agg64 x3 ----
  AggArgs ba;
  for (int b = 0; b < 3; ++b) {
    ba.x[b] = x2[b];
    ba.bias[b] = (const float*)d_in[b * 7 + 6];
    ba.out[b] = comb;  // only out[0] used
  }
  ba.out[0] = comb;
  ba.dinv3 = dinv3;
  ba.pc = pc;
  ba.off3 = off3;
  ba.csr = csr;
  agg64x3_kernel<<<3 * ABc, 256, 0, stream>>>(ba);

  // ---- fuse + pred ----
  fuse_kernel<<<GXc, 256, 10240, stream>>>(comb, wft, (const float*)d_in[22],
                                           (const float*)d_in[23], (const float*)d_in[24],
                                           (float*)d_out);
}